// Round 2
// baseline (311.772 us; speedup 1.0000x reference)
//
#include <hip/hip_runtime.h>
#include <hip/hip_bf16.h>
#include <stdint.h>

// IterativeSequential2D: N=16 blocks, D=256, B=2048, ITERS=3, banded mask j<=i+1.
// Strategy: bf16 MFMA (16x16x32), fp32 accumulate.
//   pass0: x0 -> bf16 (ws), bias_full[m,e] = sum_{j<=m+1} b[m,j,e]
//   iter1: Y0 = relu(x0 @ W[m,0]^T + b[m,0])           (bf16 out, ws)
//   iter2: Y1 = relu(concat_n Y0[n] @ W[m,n]^T + bias_full)  (bf16 out, ws)
//   iter3: out = same as iter2 but fp32 out to d_out
// GEMM: 128x128 tile, BK=64, 4 waves (64x64 each), double-buffered LDS (64KB),
// XOR-swizzled LDS rows (byte ^= (row&7)<<4) to kill the 128B-stride bank conflict.
// A staged via global_load_lds (16B, pre-swizzled global source); W reg-staged
// fp32->bf16 with swizzled ds_write_b128.

#define DD    256
#define NBLK  16
#define BATCH 2048

typedef __attribute__((ext_vector_type(8))) short  bf16x8;
typedef __attribute__((ext_vector_type(8))) __bf16 bfv8;
typedef __attribute__((ext_vector_type(4))) float  f32x4;

__device__ __forceinline__ unsigned short f2bf(float f) {
  return __builtin_bit_cast(unsigned short, (__bf16)f);
}

__device__ __forceinline__ void gload_lds16(const unsigned short* g, unsigned short* l) {
  __builtin_amdgcn_global_load_lds((const __attribute__((address_space(1))) void*)g,
                                   (__attribute__((address_space(3))) void*)l, 16, 0, 0);
}

__device__ __forceinline__ bf16x8 cvt8(float4 lo, float4 hi) {
  bfv8 t;
  t[0] = (__bf16)lo.x; t[1] = (__bf16)lo.y; t[2] = (__bf16)lo.z; t[3] = (__bf16)lo.w;
  t[4] = (__bf16)hi.x; t[5] = (__bf16)hi.y; t[6] = (__bf16)hi.z; t[7] = (__bf16)hi.w;
  return __builtin_bit_cast(bf16x8, t);
}

// ---------------- pass 0 kernels ----------------

__global__ void cvt_x0_kernel(const float* __restrict__ x, unsigned short* __restrict__ y) {
  int i = blockIdx.x * 256 + threadIdx.x;   // over float4 chunks, 131072 total
  float4 v = ((const float4*)x)[i];
  ushort4 o;
  o.x = f2bf(v.x); o.y = f2bf(v.y); o.z = f2bf(v.z); o.w = f2bf(v.w);
  ((ushort4*)y)[i] = o;
}

__global__ void bias_full_kernel(const float* __restrict__ b, float* __restrict__ bf) {
  int idx = blockIdx.x * 256 + threadIdx.x;  // 4096 total
  int m = idx >> 8, e = idx & 255;
  int nb = (m + 2 < NBLK) ? m + 2 : NBLK;
  float s = 0.f;
  for (int j = 0; j < nb; ++j) s += b[(m * NBLK + j) * DD + e];
  bf[idx] = s;
}

// ---------------- main GEMM ----------------
// OUT_BF16=1 -> bf16 output (ws), 0 -> fp32 output (d_out)

template <int OUT_BF16>
__global__ __launch_bounds__(256, 2) void gemm_step(
    const unsigned short* __restrict__ A,   // bf16 activations: [B,D] (iter1) or [N,B,D]
    const float* __restrict__ Wg,           // [N,N,D,D] fp32
    const float* __restrict__ bias,         // bias[m*bias_stride + e]
    int bias_stride,
    long a_nstride,                         // elems between A n-blocks (0 or B*D)
    int nb_mode,                            // 0: nb=1; 1: nb=min(m+2,16)
    void* __restrict__ Out)
{
  __shared__ unsigned short ldsA[2][128 * 64];
  __shared__ unsigned short ldsW[2][128 * 64];

  const int tid  = threadIdx.x;
  const int wave = tid >> 6;
  const int lane = tid & 63;

  // XCD-bijective swizzle (512 = 8*64) + heavy/light m pairing per XCD.
  int bid = blockIdx.x;
  int swz = (bid & 7) * 64 + (bid >> 3);
  int mi_ = swz >> 5;
  const int m = (int)((0x8796A5B4C3D2E1F0ULL >> (mi_ * 4)) & 15);  // {0,15,1,14,...}
  int rest = swz & 31;
  const int btile = rest >> 1;
  const int etile = rest & 1;
  const int nb = nb_mode ? ((m + 2 < NBLK) ? m + 2 : NBLK) : 1;
  const int nt = nb << 2;   // K-steps of 64 (256 per block)

  const int brow0 = btile * 128;
  const int ecol0 = etile * 128;
  const int wr = (wave >> 1) & 1;
  const int wc = wave & 1;

  // --- A staging constants: 4 global_load_lds (1KB each) per wave ---
  long a_goff[4];
  int  a_lds[4];
#pragma unroll
  for (int i = 0; i < 4; ++i) {
    int inst  = wave * 4 + i;
    int row   = inst * 8 + (lane >> 3);            // tile row (b-dim)
    int chunk = (lane & 7) ^ (row & 7);            // pre-swizzled global 16B chunk
    a_goff[i] = (long)(brow0 + row) * DD + chunk * 8;
    a_lds[i]  = inst * 512;                        // linear LDS dest (8 rows)
  }

  // --- W staging constants: 4 units/thread, each 2x float4 -> 1x ds_write_b128 ---
  long w_goff[4];
  int  w_lds[4];
#pragma unroll
  for (int u = 0; u < 4; ++u) {
    int cid = tid + 256 * u;                       // 0..1023
    int row = cid >> 3;                            // e-row in tile
    int c16 = cid & 7;                             // 16B chunk within row
    w_goff[u] = (long)(ecol0 + row) * DD + c16 * 8;          // fp32 elems
    w_lds[u]  = row * 64 + ((c16 ^ (row & 7)) * 8);          // swizzled dest
  }

  // --- fragment read offsets (XOR-swizzled) ---
  int offA[4][2], offW[4][2];
#pragma unroll
  for (int f = 0; f < 4; ++f) {
    int ra = wr * 64 + f * 16 + (lane & 15);
    int rw = wc * 64 + f * 16 + (lane & 15);
#pragma unroll
    for (int ks = 0; ks < 2; ++ks) {
      int byteoff = ks * 64 + (lane >> 4) * 16;
      offA[f][ks] = ra * 64 + (((byteoff ^ ((ra & 7) << 4))) >> 1);
      offW[f][ks] = rw * 64 + (((byteoff ^ ((rw & 7) << 4))) >> 1);
    }
  }

  f32x4 acc[4][4];
#pragma unroll
  for (int i = 0; i < 4; ++i)
#pragma unroll
    for (int j = 0; j < 4; ++j) acc[i][j] = (f32x4){0.f, 0.f, 0.f, 0.f};

  const long wm_base = (long)m * NBLK * (DD * DD);

  // prologue: stage t=0 into buf 0
  {
#pragma unroll
    for (int i = 0; i < 4; ++i)
      gload_lds16(A + a_goff[i], &ldsA[0][a_lds[i]]);
    const float* Wn = Wg + wm_base;   // n=0, kk=0
#pragma unroll
    for (int u = 0; u < 4; ++u) {
      float4 lo = *(const float4*)(Wn + w_goff[u]);
      float4 hi = *(const float4*)(Wn + w_goff[u] + 4);
      *(bf16x8*)&ldsW[0][w_lds[u]] = cvt8(lo, hi);
    }
  }
  __syncthreads();

  int cur = 0;
  for (int t = 0; t < nt; ++t) {
    const int nxt = cur ^ 1;
    const bool has_next = (t + 1 < nt);
    float4 wlo[4], whi[4];
    if (has_next) {
      int n2  = (t + 1) >> 2;
      int kk2 = ((t + 1) & 3) * 64;
      const unsigned short* An = A + (long)n2 * a_nstride + kk2;
#pragma unroll
      for (int i = 0; i < 4; ++i)
        gload_lds16(An + a_goff[i], &ldsA[nxt][a_lds[i]]);
      const float* Wn = Wg + wm_base + (long)n2 * (DD * DD) + kk2;
#pragma unroll
      for (int u = 0; u < 4; ++u) {
        wlo[u] = *(const float4*)(Wn + w_goff[u]);
        whi[u] = *(const float4*)(Wn + w_goff[u] + 4);
      }
    }
    // compute on buf[cur]
#pragma unroll
    for (int ks = 0; ks < 2; ++ks) {
      bf16x8 af[4], wf[4];
#pragma unroll
      for (int f = 0; f < 4; ++f) af[f] = *(const bf16x8*)&ldsA[cur][offA[f][ks]];
#pragma unroll
      for (int f = 0; f < 4; ++f) wf[f] = *(const bf16x8*)&ldsW[cur][offW[f][ks]];
#pragma unroll
      for (int i = 0; i < 4; ++i)
#pragma unroll
        for (int j = 0; j < 4; ++j)
          acc[i][j] = __builtin_amdgcn_mfma_f32_16x16x32_bf16(af[i], wf[j], acc[i][j], 0, 0, 0);
    }
    if (has_next) {
#pragma unroll
      for (int u = 0; u < 4; ++u)
        *(bf16x8*)&ldsW[nxt][w_lds[u]] = cvt8(wlo[u], whi[u]);
    }
    __syncthreads();
    cur = nxt;
  }

  // epilogue: bias + relu + store
  const long outbase = (long)m * BATCH * DD;
  const int  rowbase = brow0 + wr * 64;
  const int  colbase = ecol0 + wc * 64;
#pragma unroll
  for (int j = 0; j < 4; ++j) {
    const int col = colbase + j * 16 + (lane & 15);
    const float bv = bias[m * bias_stride + col];
#pragma unroll
    for (int i = 0; i < 4; ++i) {
      const int row0 = rowbase + i * 16 + ((lane >> 4) << 2);
#pragma unroll
      for (int r = 0; r < 4; ++r) {
        float v = acc[i][j][r] + bv;
        v = v > 0.f ? v : 0.f;
        long idx = outbase + (long)(row0 + r) * DD + col;
        if (OUT_BF16) ((unsigned short*)Out)[idx] = f2bf(v);
        else          ((float*)Out)[idx] = v;
      }
    }
  }
}

// ---------------- launcher ----------------

extern "C" void kernel_launch(void* const* d_in, const int* in_sizes, int n_in,
                              void* d_out, int out_size, void* d_ws, size_t ws_size,
                              hipStream_t stream) {
  const float* x0 = (const float*)d_in[0];
  const float* W  = (const float*)d_in[1];
  const float* b  = (const float*)d_in[2];
  float* out = (float*)d_out;

  char* ws = (char*)d_ws;
  unsigned short* x0b  = (unsigned short*)ws;                       // 1 MB
  unsigned short* Y0   = (unsigned short*)(ws + (1ull << 20));      // 16 MB
  unsigned short* Y1   = (unsigned short*)(ws + (17ull << 20));     // 16 MB
  float* bias_full     = (float*)(ws + (33ull << 20));              // 16 KB

  cvt_x0_kernel<<<512, 256, 0, stream>>>(x0, x0b);
  bias_full_kernel<<<16, 256, 0, stream>>>(b, bias_full);

  // iter 1: A = x0b [B,D], nb=1, bias = b[m,0,:] (stride 16*256)
  gemm_step<1><<<512, 256, 0, stream>>>(x0b, W, b, NBLK * DD, 0L, 0, (void*)Y0);
  // iter 2: A = Y0 [N,B,D], nb = min(m+2,16), bias_full (stride 256)
  gemm_step<1><<<512, 256, 0, stream>>>(Y0, W, bias_full, DD, (long)BATCH * DD, 1, (void*)Y1);
  // iter 3: same, fp32 output
  gemm_step<0><<<512, 256, 0, stream>>>(Y1, W, bias_full, DD, (long)BATCH * DD, 1, (void*)out);
}

// Round 4
// 251.783 us; speedup vs baseline: 1.2383x; 1.2383x over previous
//
#include <hip/hip_runtime.h>
#include <hip/hip_bf16.h>
#include <stdint.h>

// IterativeSequential2D: N=16 blocks, D=256, B=2048, ITERS=3, banded mask j<=i+1.
// bf16 MFMA (16x16x32), fp32 accumulate.
// v3: pre-convert the 151 present W blocks to packed bf16 (ws), then stage BOTH
// operands with global_load_lds width=16 (pre-swizzled global source, linear LDS
// dest, XOR-swizzled reads). Falls back to the v2 fp32-W path if ws too small.

#define DD    256
#define NBLK  16
#define BATCH 2048

typedef __attribute__((ext_vector_type(8))) short  bf16x8;
typedef __attribute__((ext_vector_type(8))) __bf16 bfv8;
typedef __attribute__((ext_vector_type(4))) float  f32x4;

// prefix offsets of packed present blocks: P[m] = sum_{k<m} min(k+2,16); P[16]=151
__device__ __constant__ int Pofs[17] = {0,2,5,9,14,20,27,35,44,54,65,77,90,104,119,135,151};

__device__ __forceinline__ unsigned short f2bf(float f) {
  return __builtin_bit_cast(unsigned short, (__bf16)f);
}

__device__ __forceinline__ void gload_lds16(const unsigned short* g, unsigned short* l) {
  __builtin_amdgcn_global_load_lds((const __attribute__((address_space(1))) void*)g,
                                   (__attribute__((address_space(3))) void*)l, 16, 0, 0);
}

__device__ __forceinline__ bf16x8 cvt8(float4 lo, float4 hi) {
  bfv8 t;
  t[0] = (__bf16)lo.x; t[1] = (__bf16)lo.y; t[2] = (__bf16)lo.z; t[3] = (__bf16)lo.w;
  t[4] = (__bf16)hi.x; t[5] = (__bf16)hi.y; t[6] = (__bf16)hi.z; t[7] = (__bf16)hi.w;
  return __builtin_bit_cast(bf16x8, t);
}

// ---------------- pass 0 kernels ----------------

__global__ void cvt_x0_kernel(const float* __restrict__ x, unsigned short* __restrict__ y) {
  int i = blockIdx.x * 256 + threadIdx.x;   // float4 chunks, 131072 total
  float4 v = ((const float4*)x)[i];
  ushort4 o;
  o.x = f2bf(v.x); o.y = f2bf(v.y); o.z = f2bf(v.z); o.w = f2bf(v.w);
  ((ushort4*)y)[i] = o;
}

__global__ void bias_full_kernel(const float* __restrict__ b, float* __restrict__ bf) {
  int idx = blockIdx.x * 256 + threadIdx.x;  // 4096 total
  int m = idx >> 8, e = idx & 255;
  int nb = (m + 2 < NBLK) ? m + 2 : NBLK;
  float s = 0.f;
  for (int j = 0; j < nb; ++j) s += b[(m * NBLK + j) * DD + e];
  bf[idx] = s;
}

// convert present W blocks fp32 -> packed bf16. grid = 151*32 wgs of 256.
__global__ void cvt_W_kernel(const float* __restrict__ W, unsigned short* __restrict__ Wb) {
  int p = blockIdx.x >> 5;          // packed block 0..150
  int m = 0;
#pragma unroll
  for (int k = 1; k <= 15; ++k) if (p >= Pofs[k]) m = k;
  int n = p - Pofs[m];
  long idx = (long)(blockIdx.x & 31) * 2048 + threadIdx.x * 8;   // elem within 65536
  const float* src = W + (long)(m * NBLK + n) * (DD * DD) + idx;
  float4 lo = *(const float4*)src;
  float4 hi = *(const float4*)(src + 4);
  *(bf16x8*)(Wb + (long)p * (DD * DD) + idx) = cvt8(lo, hi);
}

// ---------------- main GEMM, bf16 W (packed) ----------------
// OUT_BF16=1 -> bf16 output (ws), 0 -> fp32 output (d_out)

template <int OUT_BF16>
__global__ __launch_bounds__(256, 2) void gemm_step2(
    const unsigned short* __restrict__ A,    // bf16: [B,D] (iter1) or [N,B,D]
    const unsigned short* __restrict__ Wb,   // packed bf16 blocks [151][D][D]
    const float* __restrict__ bias,          // bias[m*bias_stride + e]
    int bias_stride,
    long a_nstride,                          // elems between A n-blocks (0 or B*D)
    int nb_mode,                             // 0: nb=1; 1: nb=min(m+2,16)
    void* __restrict__ Out)
{
  __shared__ unsigned short ldsA[2][128 * 64];
  __shared__ unsigned short ldsW[2][128 * 64];

  const int tid  = threadIdx.x;
  const int wave = tid >> 6;
  const int lane = tid & 63;

  // XCD-bijective swizzle (512 = 8*64) + heavy/light m pairing per XCD.
  int bid = blockIdx.x;
  int swz = (bid & 7) * 64 + (bid >> 3);
  int mi_ = swz >> 5;
  const int m = (int)((0x8796A5B4C3D2E1F0ULL >> (mi_ * 4)) & 15);  // {0,15,1,14,...}
  int rest = swz & 31;
  const int btile = rest >> 1;
  const int etile = rest & 1;
  const int nb = nb_mode ? ((m + 2 < NBLK) ? m + 2 : NBLK) : 1;
  const int nt = nb << 2;   // K-steps of 64

  const int brow0 = btile * 128;
  const int ecol0 = etile * 128;
  const int wr = (wave >> 1) & 1;
  const int wc = wave & 1;

  // staging: per wave 4 gload_lds for A + 4 for W; identical geometry
  // (tile row stride = DD elems bf16), pre-swizzled 16B chunk in global source.
  long a_goff[4], w_goff[4];
  int  s_lds[4];
#pragma unroll
  for (int i = 0; i < 4; ++i) {
    int inst  = wave * 4 + i;
    int row   = inst * 8 + (lane >> 3);
    int chunk = (lane & 7) ^ (row & 7);
    a_goff[i] = (long)(brow0 + row) * DD + chunk * 8;
    w_goff[i] = (long)(ecol0 + row) * DD + chunk * 8;
    s_lds[i]  = inst * 512;
  }

  // fragment read offsets (XOR-swizzled)
  int offA[4][2], offW[4][2];
#pragma unroll
  for (int f = 0; f < 4; ++f) {
    int ra = wr * 64 + f * 16 + (lane & 15);
    int rw = wc * 64 + f * 16 + (lane & 15);
#pragma unroll
    for (int ks = 0; ks < 2; ++ks) {
      int byteoff = ks * 64 + (lane >> 4) * 16;
      offA[f][ks] = ra * 64 + ((byteoff ^ ((ra & 7) << 4)) >> 1);
      offW[f][ks] = rw * 64 + ((byteoff ^ ((rw & 7) << 4)) >> 1);
    }
  }

  f32x4 acc[4][4];
#pragma unroll
  for (int i = 0; i < 4; ++i)
#pragma unroll
    for (int j = 0; j < 4; ++j) acc[i][j] = (f32x4){0.f, 0.f, 0.f, 0.f};

  const unsigned short* Wrow = Wb + (long)Pofs[m] * (DD * DD);

  // prologue: stage t=0 into buf 0
#pragma unroll
  for (int i = 0; i < 4; ++i) {
    gload_lds16(A + a_goff[i],    &ldsA[0][s_lds[i]]);
    gload_lds16(Wrow + w_goff[i], &ldsW[0][s_lds[i]]);
  }
  __syncthreads();

  int cur = 0;
  for (int t = 0; t < nt; ++t) {
    const int nxt = cur ^ 1;
    if (t + 1 < nt) {
      int n2  = (t + 1) >> 2;
      int kk2 = ((t + 1) & 3) * 64;
      const unsigned short* An = A + (long)n2 * a_nstride + kk2;
      const unsigned short* Wn = Wrow + (long)n2 * (DD * DD) + kk2;
#pragma unroll
      for (int i = 0; i < 4; ++i) {
        gload_lds16(An + a_goff[i], &ldsA[nxt][s_lds[i]]);
        gload_lds16(Wn + w_goff[i], &ldsW[nxt][s_lds[i]]);
      }
    }
#pragma unroll
    for (int ks = 0; ks < 2; ++ks) {
      bf16x8 af[4], wf[4];
#pragma unroll
      for (int f = 0; f < 4; ++f) af[f] = *(const bf16x8*)&ldsA[cur][offA[f][ks]];
#pragma unroll
      for (int f = 0; f < 4; ++f) wf[f] = *(const bf16x8*)&ldsW[cur][offW[f][ks]];
#pragma unroll
      for (int i = 0; i < 4; ++i)
#pragma unroll
        for (int j = 0; j < 4; ++j)
          acc[i][j] = __builtin_amdgcn_mfma_f32_16x16x32_bf16(af[i], wf[j], acc[i][j], 0, 0, 0);
    }
    __syncthreads();
    cur = nxt;
  }

  // epilogue: bias + relu + store
  const long outbase = (long)m * BATCH * DD;
  const int  rowbase = brow0 + wr * 64;
  const int  colbase = ecol0 + wc * 64;
#pragma unroll
  for (int j = 0; j < 4; ++j) {
    const int col = colbase + j * 16 + (lane & 15);
    const float bv = bias[m * bias_stride + col];
#pragma unroll
    for (int i = 0; i < 4; ++i) {
      const int row0 = rowbase + i * 16 + ((lane >> 4) << 2);
#pragma unroll
      for (int r = 0; r < 4; ++r) {
        float v = acc[i][j][r] + bv;
        v = v > 0.f ? v : 0.f;
        long idx = outbase + (long)(row0 + r) * DD + col;
        if (OUT_BF16) ((unsigned short*)Out)[idx] = f2bf(v);
        else          ((float*)Out)[idx] = v;
      }
    }
  }
}

// ---------------- fallback GEMM (v2, fp32 W) ----------------

template <int OUT_BF16>
__global__ __launch_bounds__(256, 2) void gemm_step(
    const unsigned short* __restrict__ A,
    const float* __restrict__ Wg,
    const float* __restrict__ bias,
    int bias_stride, long a_nstride, int nb_mode,
    void* __restrict__ Out)
{
  __shared__ unsigned short ldsA[2][128 * 64];
  __shared__ unsigned short ldsW[2][128 * 64];
  const int tid  = threadIdx.x;
  const int wave = tid >> 6;
  const int lane = tid & 63;
  int bid = blockIdx.x;
  int swz = (bid & 7) * 64 + (bid >> 3);
  int mi_ = swz >> 5;
  const int m = (int)((0x8796A5B4C3D2E1F0ULL >> (mi_ * 4)) & 15);
  int rest = swz & 31;
  const int btile = rest >> 1;
  const int etile = rest & 1;
  const int nb = nb_mode ? ((m + 2 < NBLK) ? m + 2 : NBLK) : 1;
  const int nt = nb << 2;
  const int brow0 = btile * 128;
  const int ecol0 = etile * 128;
  const int wr = (wave >> 1) & 1;
  const int wc = wave & 1;

  long a_goff[4]; int a_lds[4];
#pragma unroll
  for (int i = 0; i < 4; ++i) {
    int inst  = wave * 4 + i;
    int row   = inst * 8 + (lane >> 3);
    int chunk = (lane & 7) ^ (row & 7);
    a_goff[i] = (long)(brow0 + row) * DD + chunk * 8;
    a_lds[i]  = inst * 512;
  }
  long w_goff[4]; int w_lds[4];
#pragma unroll
  for (int u = 0; u < 4; ++u) {
    int cid = tid + 256 * u;
    int row = cid >> 3;
    int c16 = cid & 7;
    w_goff[u] = (long)(ecol0 + row) * DD + c16 * 8;
    w_lds[u]  = row * 64 + ((c16 ^ (row & 7)) * 8);
  }
  int offA[4][2], offW[4][2];
#pragma unroll
  for (int f = 0; f < 4; ++f) {
    int ra = wr * 64 + f * 16 + (lane & 15);
    int rw = wc * 64 + f * 16 + (lane & 15);
#pragma unroll
    for (int ks = 0; ks < 2; ++ks) {
      int byteoff = ks * 64 + (lane >> 4) * 16;
      offA[f][ks] = ra * 64 + ((byteoff ^ ((ra & 7) << 4)) >> 1);
      offW[f][ks] = rw * 64 + ((byteoff ^ ((rw & 7) << 4)) >> 1);
    }
  }
  f32x4 acc[4][4];
#pragma unroll
  for (int i = 0; i < 4; ++i)
#pragma unroll
    for (int j = 0; j < 4; ++j) acc[i][j] = (f32x4){0.f,0.f,0.f,0.f};
  const long wm_base = (long)m * NBLK * (DD * DD);
  {
#pragma unroll
    for (int i = 0; i < 4; ++i) gload_lds16(A + a_goff[i], &ldsA[0][a_lds[i]]);
    const float* Wn = Wg + wm_base;
#pragma unroll
    for (int u = 0; u < 4; ++u) {
      float4 lo = *(const float4*)(Wn + w_goff[u]);
      float4 hi = *(const float4*)(Wn + w_goff[u] + 4);
      *(bf16x8*)&ldsW[0][w_lds[u]] = cvt8(lo, hi);
    }
  }
  __syncthreads();
  int cur = 0;
  for (int t = 0; t < nt; ++t) {
    const int nxt = cur ^ 1;
    const bool has_next = (t + 1 < nt);
    float4 wlo[4], whi[4];
    if (has_next) {
      int n2  = (t + 1) >> 2;
      int kk2 = ((t + 1) & 3) * 64;
      const unsigned short* An = A + (long)n2 * a_nstride + kk2;
#pragma unroll
      for (int i = 0; i < 4; ++i) gload_lds16(An + a_goff[i], &ldsA[nxt][a_lds[i]]);
      const float* Wn = Wg + wm_base + (long)n2 * (DD * DD) + kk2;
#pragma unroll
      for (int u = 0; u < 4; ++u) {
        wlo[u] = *(const float4*)(Wn + w_goff[u]);
        whi[u] = *(const float4*)(Wn + w_goff[u] + 4);
      }
    }
#pragma unroll
    for (int ks = 0; ks < 2; ++ks) {
      bf16x8 af[4], wf[4];
#pragma unroll
      for (int f = 0; f < 4; ++f) af[f] = *(const bf16x8*)&ldsA[cur][offA[f][ks]];
#pragma unroll
      for (int f = 0; f < 4; ++f) wf[f] = *(const bf16x8*)&ldsW[cur][offW[f][ks]];
#pragma unroll
      for (int i = 0; i < 4; ++i)
#pragma unroll
        for (int j = 0; j < 4; ++j)
          acc[i][j] = __builtin_amdgcn_mfma_f32_16x16x32_bf16(af[i], wf[j], acc[i][j], 0, 0, 0);
    }
    if (has_next) {
#pragma unroll
      for (int u = 0; u < 4; ++u)
        *(bf16x8*)&ldsW[nxt][w_lds[u]] = cvt8(wlo[u], whi[u]);
    }
    __syncthreads();
    cur = nxt;
  }
  const long outbase = (long)m * BATCH * DD;
  const int  rowbase = brow0 + wr * 64;
  const int  colbase = ecol0 + wc * 64;
#pragma unroll
  for (int j = 0; j < 4; ++j) {
    const int col = colbase + j * 16 + (lane & 15);
    const float bv = bias[m * bias_stride + col];
#pragma unroll
    for (int i = 0; i < 4; ++i) {
      const int row0 = rowbase + i * 16 + ((lane >> 4) << 2);
#pragma unroll
      for (int r = 0; r < 4; ++r) {
        float v = acc[i][j][r] + bv;
        v = v > 0.f ? v : 0.f;
        long idx = outbase + (long)(row0 + r) * DD + col;
        if (OUT_BF16) ((unsigned short*)Out)[idx] = f2bf(v);
        else          ((float*)Out)[idx] = v;
      }
    }
  }
}

// ---------------- launcher ----------------

extern "C" void kernel_launch(void* const* d_in, const int* in_sizes, int n_in,
                              void* d_out, int out_size, void* d_ws, size_t ws_size,
                              hipStream_t stream) {
  const float* x0 = (const float*)d_in[0];
  const float* W  = (const float*)d_in[1];
  const float* b  = (const float*)d_in[2];
  float* out = (float*)d_out;

  char* ws = (char*)d_ws;
  unsigned short* x0b = (unsigned short*)ws;                    // 1 MB
  unsigned short* Y0  = (unsigned short*)(ws + (1ull << 20));   // 16 MB
  unsigned short* Y1  = (unsigned short*)(ws + (17ull << 20));  // 16 MB

  const size_t wb_bytes = 151ull * DD * DD * 2;                 // 18.9 MB
  const size_t need = (33ull << 20) + wb_bytes + 16384;

  cvt_x0_kernel<<<512, 256, 0, stream>>>(x0, x0b);

  if (ws_size >= need) {
    unsigned short* Wb = (unsigned short*)(ws + (33ull << 20));
    float* bias_full   = (float*)(ws + (33ull << 20) + wb_bytes);
    bias_full_kernel<<<16, 256, 0, stream>>>(b, bias_full);
    cvt_W_kernel<<<151 * 32, 256, 0, stream>>>(W, Wb);
    gemm_step2<1><<<512, 256, 0, stream>>>(x0b, Wb, b, NBLK * DD, 0L, 0, (void*)Y0);
    gemm_step2<1><<<512, 256, 0, stream>>>(Y0, Wb, bias_full, DD, (long)BATCH * DD, 1, (void*)Y1);
    gemm_step2<0><<<512, 256, 0, stream>>>(Y1, Wb, bias_full, DD, (long)BATCH * DD, 1, (void*)out);
  } else {
    float* bias_full = (float*)(ws + (33ull << 20));
    bias_full_kernel<<<16, 256, 0, stream>>>(b, bias_full);
    gemm_step<1><<<512, 256, 0, stream>>>(x0b, W, b, NBLK * DD, 0L, 0, (void*)Y0);
    gemm_step<1><<<512, 256, 0, stream>>>(Y0, W, bias_full, DD, (long)BATCH * DD, 1, (void*)Y1);
    gemm_step<0><<<512, 256, 0, stream>>>(Y1, W, bias_full, DD, (long)BATCH * DD, 1, (void*)out);
  }
}